// Round 3
// baseline (1266.910 us; speedup 1.0000x reference)
//
#include <hip/hip_runtime.h>
#include <math.h>

#define NB 4
#define P 2048
#define DF 64
#define EPS 0.1f
#define INV_EPS 10.0f
#define MAX_ITER 50
#define NBLK 256   // 1 block per CU (cooperative, co-resident)
#define TPB 512    // 8 waves
#define RPC 16     // rows per chain per block (2 per wave)
#define NPROD 128  // producers per batch (dual-chain: each block serves 2 batches)
// base-2 log domain: creg = C * INV_EPS * log2(e); cost = sum(pi*creg)*EPS*ln2
#define SCALE 14.426950408889634f
#define C2N 0.069314718055994531f

typedef float vfloat4 __attribute__((ext_vector_type(4)));  // native vec for nt-store

#if __has_builtin(__builtin_amdgcn_exp2f)
#define EXP2(x) __builtin_amdgcn_exp2f(x)
#else
#define EXP2(x) exp2f(x)
#endif
#if __has_builtin(__builtin_amdgcn_logf)
#define LOG2(x) __builtin_amdgcn_logf(x)
#else
#define LOG2(x) log2f(x)
#endif

struct BuildMem { float xs[RPC * DF]; float ys[32 * 260]; };   // 4KB + 33.3KB
struct IterMem  { float v[P]; float m[4][P]; float s[4][P]; }; // 8KB + 64KB
struct RedMem   { float mm[8][16]; float ss[8][16]; };         // 1KB
union SMem { BuildMem b; IterMem c; RedMem r; };

// ---------------------------------------------------------------------------
// Agent-coherent (L2-bypassing, performed-at-L3) data movement. Relaxed
// atomics at AGENT scope. Visibility protocol (HW-verified rounds 0-2):
//   writer: stores -> __threadfence_block+__syncthreads (vmcnt drain; a
//           retired sc1 store is visible at L3) -> t0 stamps flag (plain store)
//   reader: poll flag(s) in parallel -> __syncthreads -> sc1 data loads
// Per-producer flag STORES (not RMW counters): 64 serialized fetch_adds to
// one address cost ~µs per sync; parallel stores + parallel polls do not.
// ---------------------------------------------------------------------------
__device__ __forceinline__ void flag_store(unsigned* f, unsigned v) {
  __hip_atomic_store(f, v, __ATOMIC_RELAXED, __HIP_MEMORY_SCOPE_AGENT);
}
__device__ __forceinline__ unsigned flag_load(unsigned* f) {
  return __hip_atomic_load(f, __ATOMIC_RELAXED, __HIP_MEMORY_SCOPE_AGENT);
}
__device__ __forceinline__ float2 load_f2_agent(float2* p) {
  unsigned long long bits = __hip_atomic_load((unsigned long long*)p,
      __ATOMIC_RELAXED, __HIP_MEMORY_SCOPE_AGENT);
  return make_float2(__uint_as_float((unsigned)bits),
                     __uint_as_float((unsigned)(bits >> 32)));
}
__device__ __forceinline__ float load_f_agent(float* p) {
  return __hip_atomic_load(p, __ATOMIC_RELAXED, __HIP_MEMORY_SCOPE_AGENT);
}
__device__ __forceinline__ void store_f_agent(float* p, float v) {
  __hip_atomic_store(p, v, __ATOMIC_RELAXED, __HIP_MEMORY_SCOPE_AGENT);
}

// LSE2 merge of (M,S) with (om,os): one exp2 (the max side's factor is 1).
__device__ __forceinline__ void lse_merge(float& M, float& S, float om, float os) {
  float d = EXP2(-fabsf(M - om));
  float Sn = (M >= om) ? fmaf(os, d, S) : fmaf(S, d, os);
  M = fmaxf(M, om);
  S = Sn;
}

// ---------------------------------------------------------------------------
// compute stage for one chain: wait V(k) [all 128 reducer flags], stage V to
// LDS, u-update (2 rows/wave), v-partials, 8->4->1 LDS combine, post one
// float L = M + log2(S) per column (swizzled storage order), stamp pf.
// ---------------------------------------------------------------------------
__device__ __forceinline__ void c_stage(
    int k, int t, int w, int l, int rb,
    const float (&cr)[2][32], float (&Uo)[2],
    float* Vgc, float* post_row, unsigned* vfc, unsigned* pf_mine,
    SMem& sm, float l2mu) {
  if (t < NPROD) {
    unsigned* f = vfc + t;
    while (flag_load(f) < (unsigned)k) __builtin_amdgcn_s_sleep(1);
  }
  __syncthreads();
  {  // stage V -> LDS (b128 store, conflict-free)
    float2 a = load_f2_agent((float2*)(Vgc + 4 * t));
    float2 b2 = load_f2_agent((float2*)(Vgc + 4 * t + 2));
    vfloat4 vv = {a.x, a.y, b2.x, b2.y};
    *(vfloat4*)&sm.c.v[4 * t] = vv;
  }
  __syncthreads();
  float vreg[32];
#pragma unroll
  for (int kk = 0; kk < 8; ++kk) {
    float4 v4 = *(const float4*)&sm.c.v[256 * kk + 4 * l];
    vreg[4 * kk + 0] = v4.x; vreg[4 * kk + 1] = v4.y;
    vreg[4 * kk + 2] = v4.z; vreg[4 * kk + 3] = v4.w;
  }
  // u-update: U_i = l2mu - LSE2_j(V_j - C2_ij)
#pragma unroll
  for (int r = 0; r < 2; ++r) {
    float arg[32];
    float m = -3.4e38f;
#pragma unroll
    for (int i = 0; i < 32; ++i) {
      arg[i] = vreg[i] - cr[r][i];
      m = fmaxf(m, arg[i]);
    }
#pragma unroll
    for (int off = 32; off; off >>= 1) m = fmaxf(m, __shfl_xor(m, off));
    float s = 0.f;
#pragma unroll
    for (int i = 0; i < 32; ++i) s += EXP2(arg[i] - m);
#pragma unroll
    for (int off = 32; off; off >>= 1) s += __shfl_xor(s, off);
    Uo[r] = l2mu - (m + LOG2(s));
  }
  // v-partials over this wave's 2 rows: one exp2 per column
  float pm[32], ps[32];
#pragma unroll
  for (int i = 0; i < 32; ++i) {
    float a0 = Uo[0] - cr[0][i];
    float a1 = Uo[1] - cr[1][i];
    pm[i] = fmaxf(a0, a1);
    ps[i] = 1.f + EXP2(-fabsf(a0 - a1));
  }
  // combine 8 waves -> 4 -> 1 via LDS (swizzled idx = 256k + 64e + l)
  if (w >= 4) {
#pragma unroll
    for (int i = 0; i < 32; ++i) {
      int idx = 256 * (i >> 2) + 64 * (i & 3) + l;
      sm.c.m[w - 4][idx] = pm[i];
      sm.c.s[w - 4][idx] = ps[i];
    }
  }
  __syncthreads();
  if (w < 4) {
#pragma unroll
    for (int i = 0; i < 32; ++i) {
      int idx = 256 * (i >> 2) + 64 * (i & 3) + l;
      float M = pm[i], S = ps[i];
      lse_merge(M, S, sm.c.m[w][idx], sm.c.s[w][idx]);
      sm.c.m[w][idx] = M;
      sm.c.s[w][idx] = S;
    }
  }
  __syncthreads();
  // post single-float LSE partial per column, swizzled storage order
#pragma unroll
  for (int q = 0; q < 4; ++q) {
    int idx = t + 512 * q;  // storage order -> coalesced post
    float m0 = sm.c.m[0][idx], m1 = sm.c.m[1][idx];
    float m2 = sm.c.m[2][idx], m3 = sm.c.m[3][idx];
    float s0 = sm.c.s[0][idx], s1 = sm.c.s[1][idx];
    float s2 = sm.c.s[2][idx], s3 = sm.c.s[3][idx];
    float M = fmaxf(fmaxf(m0, m1), fmaxf(m2, m3));
    float S = s0 * EXP2(m0 - M) + s1 * EXP2(m1 - M)
            + s2 * EXP2(m2 - M) + s3 * EXP2(m3 - M);
    store_f_agent(post_row + idx, M + LOG2(S));
  }
  __threadfence_block();  // vmcnt drain: retired sc1 stores visible at L3
  __syncthreads();
  if (t == 0) flag_store(pf_mine, (unsigned)(k + 1));
}

// ---------------------------------------------------------------------------
// reduce stage for one chain: wait all 128 producer flags, merge 128 partials
// for this block's 16 storage slots, write V segment (un-swizzled), stamp vf.
// thread t: slot cs = t&15, producer group pg = t>>4 (4 producers each);
// in-wave shfl merges 16 producers; cross-wave via 1KB LDS.
// ---------------------------------------------------------------------------
__device__ __forceinline__ void r_stage(
    int k, int t, int w, int l, int rb,
    float* partc, float* Vgc, unsigned* pfc, unsigned* vf_mine,
    SMem& sm, float l2mu) {
  if (t < NPROD) {
    unsigned* f = pfc + t;
    while (flag_load(f) < (unsigned)(k + 1)) __builtin_amdgcn_s_sleep(1);
  }
  __syncthreads();
  const int cs = t & 15;
  const int pg = t >> 4;
  const int sbase = rb * 16 + cs;
  float L0 = load_f_agent(partc + (size_t)(pg * 4 + 0) * P + sbase);
  float L1 = load_f_agent(partc + (size_t)(pg * 4 + 1) * P + sbase);
  float L2 = load_f_agent(partc + (size_t)(pg * 4 + 2) * P + sbase);
  float L3 = load_f_agent(partc + (size_t)(pg * 4 + 3) * P + sbase);
  float M = fmaxf(fmaxf(L0, L1), fmaxf(L2, L3));
  float S = EXP2(L0 - M) + EXP2(L1 - M) + EXP2(L2 - M) + EXP2(L3 - M);
  {  // merge 4 producer-groups within the wave (t bits 4,5 == l bits 4,5)
    float Mo = __shfl_xor(M, 16), So = __shfl_xor(S, 16);
    lse_merge(M, S, Mo, So);
    Mo = __shfl_xor(M, 32); So = __shfl_xor(S, 32);
    lse_merge(M, S, Mo, So);
  }
  if (l < 16) { sm.r.mm[w][l] = M; sm.r.ss[w][l] = S; }
  __syncthreads();
  if (t < 16) {
    float Mm = sm.r.mm[0][t], Ss = sm.r.ss[0][t];
#pragma unroll
    for (int w2 = 1; w2 < 8; ++w2)
      lse_merge(Mm, Ss, sm.r.mm[w2][t], sm.r.ss[w2][t]);
    int s = rb * 16 + t;
    int col = (s & ~255) + 4 * (s & 63) + ((s >> 6) & 3);  // un-swizzle
    store_f_agent(Vgc + col, l2mu - (Mm + LOG2(Ss)));
  }
  __threadfence_block();
  __syncthreads();
  if (t == 0) flag_store(vf_mine, (unsigned)(k + 1));
}

// ---------------------------------------------------------------------------
// Persistent cooperative kernel, dual-chain: each block owns 16 rows of TWO
// batches (g = b>>7: batches 2g, 2g+1). Per loop iteration:
//   C_A(k) ; R_B(k) ; R_A(k) ; C_B(k+1)
// -> every inter-block flag wait is buffered by exactly one stage of the
// other (independent) chain, hiding sync latency under compute.
// ---------------------------------------------------------------------------
__global__ __launch_bounds__(TPB, 2) void sinkhorn_all(
    const float* __restrict__ x, const float* __restrict__ y,
    float* __restrict__ Cout, float* __restrict__ pi,
    float* __restrict__ cost, float* __restrict__ part,
    float* __restrict__ Vg, unsigned* __restrict__ flags, float l2mu) {
  __shared__ SMem sm;
  const int t = threadIdx.x;
  const int w = t >> 6;
  const int l = t & 63;
  const int b = blockIdx.x;
  const int g = b >> 7;     // batch-pair group
  const int rb = b & 127;   // producer/reducer index within each batch
  const int i0 = rb * RPC;
  const int n0 = 2 * g, n1 = 2 * g + 1;
  unsigned* pf = flags;         // [4][128] partials-ready stamps
  unsigned* vf = flags + 512;   // [4][128] V-ready stamps
  unsigned* ef = flags + 1024;  // [256] epilogue rendezvous

  float creg[2][2][32];  // [chain][row-of-wave][col-slot], C*INV_EPS*log2e
  float U[2][2];

  // ---------------- build phase (both chains) ----------------
#pragma unroll
  for (int c = 0; c < 2; ++c) {
    const int n = 2 * g + c;
    const size_t xyb = (size_t)n * P * DF;
    const size_t cb = (size_t)n * P * P;
    __syncthreads();  // protect xs/ys reuse from previous chain
    if (t < 256) {
      const int rr = t >> 4, d4 = (t & 15) * 4;
      float4 xv = *(const float4*)(x + xyb + (size_t)(i0 + rr) * DF + d4);
      sm.b.xs[rr * DF + d4 + 0] = xv.x;
      sm.b.xs[rr * DF + d4 + 1] = xv.y;
      sm.b.xs[rr * DF + d4 + 2] = xv.z;
      sm.b.xs[rr * DF + d4 + 3] = xv.w;
    }
    const int cl = t >> 1;         // y-row within 256-col chunk
    const int db = (t & 1) * 16;   // d-offset within 32-d half
#pragma unroll
    for (int k = 0; k < 8; ++k) {
      float acc[2][4];
#pragma unroll
      for (int r = 0; r < 2; ++r)
        acc[r][0] = acc[r][1] = acc[r][2] = acc[r][3] = 0.f;
#pragma unroll
      for (int h = 0; h < 2; ++h) {
        __syncthreads();  // protect previous ys tile use (covers xs too)
        {
          const float* yp = y + xyb + (size_t)(256 * k + cl) * DF + 32 * h + db;
          float4 q0 = *(const float4*)(yp + 0);
          float4 q1 = *(const float4*)(yp + 4);
          float4 q2 = *(const float4*)(yp + 8);
          float4 q3 = *(const float4*)(yp + 12);
          float* ys = sm.b.ys;
          ys[(db + 0) * 260 + cl] = q0.x;  ys[(db + 1) * 260 + cl] = q0.y;
          ys[(db + 2) * 260 + cl] = q0.z;  ys[(db + 3) * 260 + cl] = q0.w;
          ys[(db + 4) * 260 + cl] = q1.x;  ys[(db + 5) * 260 + cl] = q1.y;
          ys[(db + 6) * 260 + cl] = q1.z;  ys[(db + 7) * 260 + cl] = q1.w;
          ys[(db + 8) * 260 + cl] = q2.x;  ys[(db + 9) * 260 + cl] = q2.y;
          ys[(db + 10) * 260 + cl] = q2.z; ys[(db + 11) * 260 + cl] = q2.w;
          ys[(db + 12) * 260 + cl] = q3.x; ys[(db + 13) * 260 + cl] = q3.y;
          ys[(db + 14) * 260 + cl] = q3.z; ys[(db + 15) * 260 + cl] = q3.w;
        }
        __syncthreads();
#pragma unroll 8
        for (int dd = 0; dd < 32; ++dd) {
          float4 y4 = *(const float4*)&sm.b.ys[dd * 260 + 4 * l];
#pragma unroll
          for (int r = 0; r < 2; ++r) {
            float xv = sm.b.xs[(2 * w + r) * DF + 32 * h + dd];  // wave-uniform
            float d0 = xv - y4.x; acc[r][0] = fmaf(d0, d0, acc[r][0]);
            float d1 = xv - y4.y; acc[r][1] = fmaf(d1, d1, acc[r][1]);
            float d2 = xv - y4.z; acc[r][2] = fmaf(d2, d2, acc[r][2]);
            float d3 = xv - y4.w; acc[r][3] = fmaf(d3, d3, acc[r][3]);
          }
        }
      }
#pragma unroll
      for (int r = 0; r < 2; ++r) {
        vfloat4 c4 = {acc[r][0], acc[r][1], acc[r][2], acc[r][3]};
        __builtin_nontemporal_store(c4,
            (vfloat4*)(Cout + cb + (size_t)(i0 + 2 * w + r) * P + 256 * k + 4 * l));
        creg[c][r][4 * k + 0] = acc[r][0] * SCALE;
        creg[c][r][4 * k + 1] = acc[r][1] * SCALE;
        creg[c][r][4 * k + 2] = acc[r][2] * SCALE;
        creg[c][r][4 * k + 3] = acc[r][3] * SCALE;
      }
    }
  }
  __syncthreads();  // build->iter LDS union hazard

  // ---------------- pipelined Sinkhorn iterations ----------------
  float* partA = part + (size_t)n0 * NPROD * P;
  float* partB = part + (size_t)n1 * NPROD * P;
  float* VgA = Vg + n0 * P;
  float* VgB = Vg + n1 * P;
  unsigned* pfA = pf + n0 * NPROD;
  unsigned* pfB = pf + n1 * NPROD;
  unsigned* vfA = vf + n0 * NPROD;
  unsigned* vfB = vf + n1 * NPROD;
  float* postA = partA + (size_t)rb * P;
  float* postB = partB + (size_t)rb * P;

  // prologue: chain B iteration 0 (V_B(0)=0 from memset; vf>=0 trivial)
  c_stage(0, t, w, l, rb, creg[1], U[1], VgB, postB, vfB, &pfB[rb], sm, l2mu);
#pragma unroll 1
  for (int k = 0; k < MAX_ITER; ++k) {
    c_stage(k, t, w, l, rb, creg[0], U[0], VgA, postA, vfA, &pfA[rb], sm, l2mu);
    r_stage(k, t, w, l, rb, partB, VgB, pfB, &vfB[rb], sm, l2mu);
    r_stage(k, t, w, l, rb, partA, VgA, pfA, &vfA[rb], sm, l2mu);
    if (k + 1 < MAX_ITER)
      c_stage(k + 1, t, w, l, rb, creg[1], U[1], VgB, postB, vfB, &pfB[rb], sm, l2mu);
  }
  // here: U[0]=U_A(50), U[1]=U_B(50); V(50) posted by R_A(49)/R_B(49).

  // ---------------- epilogue: pi and cost ----------------
  if (t < NPROD) {  // final V for both chains (all reducers)
    unsigned* f = vfA + t;
    while (flag_load(f) < (unsigned)MAX_ITER) __builtin_amdgcn_s_sleep(1);
    f = vfB + t;
    while (flag_load(f) < (unsigned)MAX_ITER) __builtin_amdgcn_s_sleep(1);
  }
  __syncthreads();
  {  // stage V_A -> sm.c.v, V_B -> sm.c.m[0] (both must be read before pi writes)
    float2 a = load_f2_agent((float2*)(VgA + 4 * t));
    float2 b2 = load_f2_agent((float2*)(VgA + 4 * t + 2));
    vfloat4 vv = {a.x, a.y, b2.x, b2.y};
    *(vfloat4*)&sm.c.v[4 * t] = vv;
    a = load_f2_agent((float2*)(VgB + 4 * t));
    b2 = load_f2_agent((float2*)(VgB + 4 * t + 2));
    vfloat4 vv2 = {a.x, a.y, b2.x, b2.y};
    *(vfloat4*)&sm.c.m[0][4 * t] = vv2;
  }
  __syncthreads();
  // part/Vg live inside the pi region: GLOBAL rendezvous before overwrite
  if (t == 0) flag_store(&ef[b], 1u);
  if (t < 256) {
    unsigned* f = &ef[t];
    while (flag_load(f) < 1u) __builtin_amdgcn_s_sleep(1);
  }
  __syncthreads();
#pragma unroll
  for (int c = 0; c < 2; ++c) {
    const int n = 2 * g + c;
    const float* vlds = (c == 0) ? sm.c.v : sm.c.m[0];
    float cs = 0.f;
#pragma unroll
    for (int r = 0; r < 2; ++r) {
      const size_t rowb = (size_t)n * P * P + (size_t)(i0 + 2 * w + r) * P;
#pragma unroll
      for (int kk = 0; kk < 8; ++kk) {
        float4 v4 = *(const float4*)&vlds[256 * kk + 4 * l];
        vfloat4 p4;
        p4.x = EXP2(U[c][r] + v4.x - creg[c][r][4 * kk + 0]);
        p4.y = EXP2(U[c][r] + v4.y - creg[c][r][4 * kk + 1]);
        p4.z = EXP2(U[c][r] + v4.z - creg[c][r][4 * kk + 2]);
        p4.w = EXP2(U[c][r] + v4.w - creg[c][r][4 * kk + 3]);
        cs += p4.x * creg[c][r][4 * kk + 0] + p4.y * creg[c][r][4 * kk + 1]
            + p4.z * creg[c][r][4 * kk + 2] + p4.w * creg[c][r][4 * kk + 3];
        __builtin_nontemporal_store(p4, (vfloat4*)(pi + rowb + 256 * kk + 4 * l));
      }
    }
    cs *= C2N;  // creg = C*INV_EPS*log2e -> sum(pi*creg)*EPS*ln2 = sum(pi*C)
#pragma unroll
    for (int off = 32; off; off >>= 1) cs += __shfl_xor(cs, off);
    if (l == 0) atomicAdd(cost + n, cs);
  }
}

// ===========================================================================
// Fallback path (round-1 kernels, known-good) in case cooperative launch fails
// ===========================================================================
__global__ __launch_bounds__(256) void build_c(const float* __restrict__ x,
                                               const float* __restrict__ y,
                                               float* __restrict__ C,
                                               float* __restrict__ CT) {
  __shared__ float xs[DF][68];
  __shared__ float ys[DF][68];
  const int n = blockIdx.z;
  const int i0 = blockIdx.y * 64, j0 = blockIdx.x * 64;
  const int t = threadIdx.x;
  const int lr = t >> 4, c4 = (t & 15) * 4;
  const size_t xb = (size_t)n * P * DF;
  for (int rr = lr; rr < 64; rr += 16) {
    float4 xv = *(const float4*)(x + xb + (size_t)(i0 + rr) * DF + c4);
    float4 yv = *(const float4*)(y + xb + (size_t)(j0 + rr) * DF + c4);
    xs[c4 + 0][rr] = xv.x; xs[c4 + 1][rr] = xv.y;
    xs[c4 + 2][rr] = xv.z; xs[c4 + 3][rr] = xv.w;
    ys[c4 + 0][rr] = yv.x; ys[c4 + 1][rr] = yv.y;
    ys[c4 + 2][rr] = yv.z; ys[c4 + 3][rr] = yv.w;
  }
  __syncthreads();
  const int ty = t >> 4, tx = t & 15;
  float acc[4][4];
#pragma unroll
  for (int e = 0; e < 4; ++e)
#pragma unroll
    for (int f = 0; f < 4; ++f) acc[e][f] = 0.f;
#pragma unroll 4
  for (int d = 0; d < DF; ++d) {
    float4 a4 = *(const float4*)&xs[d][4 * ty];
    float4 b4 = *(const float4*)&ys[d][4 * tx];
    float av[4] = {a4.x, a4.y, a4.z, a4.w};
    float bv[4] = {b4.x, b4.y, b4.z, b4.w};
#pragma unroll
    for (int e = 0; e < 4; ++e)
#pragma unroll
      for (int f = 0; f < 4; ++f) {
        float df = av[e] - bv[f];
        acc[e][f] = fmaf(df, df, acc[e][f]);
      }
  }
  const size_t cbase = (size_t)n * P * P;
#pragma unroll
  for (int e = 0; e < 4; ++e) {
    float4 v4 = make_float4(acc[e][0], acc[e][1], acc[e][2], acc[e][3]);
    *(float4*)(C + cbase + (size_t)(i0 + 4 * ty + e) * P + (j0 + 4 * tx)) = v4;
  }
#pragma unroll
  for (int f = 0; f < 4; ++f) {
    float4 v4 = make_float4(acc[0][f], acc[1][f], acc[2][f], acc[3][f]);
    *(float4*)(CT + cbase + (size_t)(j0 + 4 * tx + f) * P + (i0 + 4 * ty)) = v4;
  }
}

__global__ __launch_bounds__(256) void lse_pass(const float* __restrict__ M,
                                                const float* __restrict__ wv_,
                                                float* __restrict__ out,
                                                float log_w) {
  __shared__ float red[8];
  const int b = blockIdx.x;
  const int n = b >> 11;
  const int t = threadIdx.x;
  const float4* row = (const float4*)(M + (size_t)b * P);
  const float4* wv = (const float4*)(wv_ + (size_t)n * P);
  float4 c0 = row[t], c1 = row[t + 256];
  float4 w0 = wv[t], w1 = wv[t + 256];
  float a[8];
  a[0] = (w0.x - c0.x) * INV_EPS; a[1] = (w0.y - c0.y) * INV_EPS;
  a[2] = (w0.z - c0.z) * INV_EPS; a[3] = (w0.w - c0.w) * INV_EPS;
  a[4] = (w1.x - c1.x) * INV_EPS; a[5] = (w1.y - c1.y) * INV_EPS;
  a[6] = (w1.z - c1.z) * INV_EPS; a[7] = (w1.w - c1.w) * INV_EPS;
  float mx = a[0];
#pragma unroll
  for (int k = 1; k < 8; ++k) mx = fmaxf(mx, a[k]);
#pragma unroll
  for (int o = 32; o > 0; o >>= 1) mx = fmaxf(mx, __shfl_xor(mx, o));
  if ((t & 63) == 0) red[t >> 6] = mx;
  __syncthreads();
  mx = fmaxf(fmaxf(red[0], red[1]), fmaxf(red[2], red[3]));
  float s = 0.f;
#pragma unroll
  for (int k = 0; k < 8; ++k) s += __expf(a[k] - mx);
#pragma unroll
  for (int o = 32; o > 0; o >>= 1) s += __shfl_xor(s, o);
  if ((t & 63) == 0) red[4 + (t >> 6)] = s;
  __syncthreads();
  if (t == 0) {
    float S = red[4] + red[5] + red[6] + red[7];
    out[b] = EPS * (log_w - (mx + __logf(S)));
  }
}

__global__ __launch_bounds__(256) void final_pass(const float* __restrict__ C,
                                                  const float* __restrict__ u,
                                                  const float* __restrict__ v,
                                                  float* __restrict__ pi,
                                                  float* __restrict__ cost) {
  __shared__ float red[4];
  const int b = blockIdx.x;
  const int n = b >> 11;
  const int t = threadIdx.x;
  const float ui = u[b];
  const float4* row = (const float4*)(C + (size_t)b * P);
  const float4* vv = (const float4*)(v + (size_t)n * P);
  float4* prow = (float4*)(pi + (size_t)b * P);
  float local = 0.f;
#pragma unroll
  for (int h = 0; h < 2; ++h) {
    float4 c = row[t + 256 * h];
    float4 vw = vv[t + 256 * h];
    float4 p;
    p.x = __expf((ui + vw.x - c.x) * INV_EPS);
    p.y = __expf((ui + vw.y - c.y) * INV_EPS);
    p.z = __expf((ui + vw.z - c.z) * INV_EPS);
    p.w = __expf((ui + vw.w - c.w) * INV_EPS);
    prow[t + 256 * h] = p;
    local += p.x * c.x + p.y * c.y + p.z * c.z + p.w * c.w;
  }
#pragma unroll
  for (int o = 32; o > 0; o >>= 1) local += __shfl_xor(local, o);
  if ((t & 63) == 0) red[t >> 6] = local;
  __syncthreads();
  if (t == 0) {
    float S = red[0] + red[1] + red[2] + red[3];
    atomicAdd(cost + n, S);
  }
}

extern "C" void kernel_launch(void* const* d_in, const int* in_sizes, int n_in,
                              void* d_out, int out_size, void* d_ws, size_t ws_size,
                              hipStream_t stream) {
  const float* x = (const float*)d_in[0];
  const float* y = (const float*)d_in[1];
  float* cost = (float*)d_out;                 // 4 floats
  float* pi = cost + 4;                        // 4*2048*2048
  float* C = pi + (size_t)NB * P * P;          // 4*2048*2048
  // scratch carved out of the pi output slot (fully overwritten by epilogue):
  float* part = pi;                                    // 4 MB of 4B partials
  float* Vg = pi + (size_t)NB * NPROD * P;             // 32 KB V vector
  unsigned* flags = (unsigned*)d_ws;                   // pf/vf/ef stamps

  (void)hipMemsetAsync(cost, 0, NB * sizeof(float), stream);
  (void)hipMemsetAsync(Vg, 0, NB * P * sizeof(float), stream);
  (void)hipMemsetAsync(flags, 0, 5120, stream);

  float lmu = logf(1.0f / (float)P + 1e-8f);    // nat log (fallback)
  float l2mu = log2f(1.0f / (float)P + 1e-8f);  // base-2 log (main)

  void* args[] = {(void*)&x, (void*)&y, (void*)&C, (void*)&pi,
                  (void*)&cost, (void*)&part, (void*)&Vg, (void*)&flags,
                  (void*)&l2mu};
  hipError_t err = hipLaunchCooperativeKernel((void*)sinkhorn_all, dim3(NBLK),
                                              dim3(TPB), args, 0, stream);
  if (err != hipSuccess) {
    // fallback: round-1 multi-kernel path (deterministically taken if coop fails)
    float* u = (float*)d_ws;
    float* v = u + NB * P;
    (void)hipMemsetAsync(v, 0, NB * P * sizeof(float), stream);
    float* CT = pi;
    build_c<<<dim3(32, 32, 4), 256, 0, stream>>>(x, y, C, CT);
    for (int it = 0; it < MAX_ITER; ++it) {
      lse_pass<<<NB * P, 256, 0, stream>>>(C, v, u, lmu);
      lse_pass<<<NB * P, 256, 0, stream>>>(CT, u, v, lmu);
    }
    final_pass<<<NB * P, 256, 0, stream>>>(C, u, v, pi, cost);
  }
}

// Round 4
// 1035.608 us; speedup vs baseline: 1.2233x; 1.2233x over previous
//
#include <hip/hip_runtime.h>
#include <math.h>

#define NB 4
#define P 2048
#define DF 64
#define EPS 0.1f
#define INV_EPS 10.0f
#define MAX_ITER 50
#define NBLK 256   // 1 block per CU (cooperative, co-resident)
#define TPB 512    // 8 waves
#define RPB 32     // rows per block (4 per wave)
#define NPROD 64   // producer/reducer blocks per batch
// base-2 log domain: creg = C * INV_EPS * log2(e); cost = sum(pi*creg)*EPS*ln2
#define SCALE 14.426950408889634f
#define C2N 0.069314718055994531f

typedef float vfloat4 __attribute__((ext_vector_type(4)));  // native vec for nt-store

#if __has_builtin(__builtin_amdgcn_exp2f)
#define EXP2(x) __builtin_amdgcn_exp2f(x)
#else
#define EXP2(x) exp2f(x)
#endif
#if __has_builtin(__builtin_amdgcn_logf)
#define LOG2(x) __builtin_amdgcn_logf(x)
#else
#define LOG2(x) log2f(x)
#endif

struct BuildMem { float xs[RPB * DF]; float ys[32 * 260]; };   // 8KB + 33.3KB
struct IterMem  { float v[P]; float m[4][P]; float s[4][P]; }; // 8KB + 64KB
struct RedMem   { float mm[8][32]; float ss[8][32]; };         // 2KB
union SMem { BuildMem b; IterMem c; RedMem r; };

// ---------------------------------------------------------------------------
// Agent-coherent (L2-bypassing, performed-at-L3) data movement. Relaxed
// atomics at AGENT scope. Visibility protocol (HW-verified rounds 0-3):
//   writer: stores -> __threadfence_block+__syncthreads (vmcnt drain; a
//           retired sc1 store is visible at L3) -> t0 stamps flag (plain store)
//   reader: poll flags in PARALLEL (one thread per flag) -> __syncthreads ->
//           sc1 data loads
// Per-producer flag STORES (not RMW counters): 64 serialized fetch_adds to
// one address serialize at the L3 atomic unit; parallel stores+polls don't.
// ---------------------------------------------------------------------------
__device__ __forceinline__ void flag_store(unsigned* f, unsigned v) {
  __hip_atomic_store(f, v, __ATOMIC_RELAXED, __HIP_MEMORY_SCOPE_AGENT);
}
__device__ __forceinline__ unsigned flag_load(unsigned* f) {
  return __hip_atomic_load(f, __ATOMIC_RELAXED, __HIP_MEMORY_SCOPE_AGENT);
}
__device__ __forceinline__ float2 load_f2_agent(float2* p) {
  unsigned long long bits = __hip_atomic_load((unsigned long long*)p,
      __ATOMIC_RELAXED, __HIP_MEMORY_SCOPE_AGENT);
  return make_float2(__uint_as_float((unsigned)bits),
                     __uint_as_float((unsigned)(bits >> 32)));
}
__device__ __forceinline__ float load_f_agent(float* p) {
  return __hip_atomic_load(p, __ATOMIC_RELAXED, __HIP_MEMORY_SCOPE_AGENT);
}
__device__ __forceinline__ void store_f_agent(float* p, float v) {
  __hip_atomic_store(p, v, __ATOMIC_RELAXED, __HIP_MEMORY_SCOPE_AGENT);
}

// LSE2 merge of (M,S) with (om,os): one exp2 (the max side's factor is 1).
__device__ __forceinline__ void lse_merge(float& M, float& S, float om, float os) {
  float d = EXP2(-fabsf(M - om));
  float Sn = (M >= om) ? fmaf(os, d, S) : fmaf(S, d, os);
  M = fmaxf(M, om);
  S = Sn;
}

// ---------------------------------------------------------------------------
// Persistent cooperative kernel: build C (+reg-resident scaled copy),
// 50 Sinkhorn iterations entirely from registers, pi/cost epilogue.
// Lane layout: wave w owns rows i0+4w..+3; lane l holds cols 256k+4l+e
// (k=0..7, e=0..3) of each of its 4 rows -> creg[4][32].
//
// SLOT ORDER: column c = 256k+4j+e maps to slot s = 256k+64e+j. Everything
// in the exchange (partials AND V) lives in slot order:
//   - partial post: coalesced (idx = t + 512q)
//   - reducer rb owns slots [rb*32, rb*32+32): loads are 128B-contiguous
//     runs per half-wave; V write is 32 CONSECUTIVE floats.
//   - consumers stage V (slot order) into LDS with b128 stores, then lane l
//     un-swizzles via 32 conflict-free scalar LDS reads at [256k+64e+l].
// ---------------------------------------------------------------------------
__global__ __launch_bounds__(TPB, 2) void sinkhorn_all(
    const float* __restrict__ x, const float* __restrict__ y,
    float* __restrict__ Cout, float* __restrict__ pi,
    float* __restrict__ cost, float* __restrict__ part,
    float* __restrict__ Vg, unsigned* __restrict__ flags, float l2mu) {
  __shared__ SMem sm;
  const int t = threadIdx.x;
  const int w = t >> 6;
  const int l = t & 63;
  const int b = blockIdx.x;
  const int n = b >> 6;    // batch
  const int rb = b & 63;   // block within batch
  const int i0 = rb * RPB;
  const size_t xyb = (size_t)n * P * DF;
  const size_t cb = (size_t)n * P * P;
  unsigned* pf = flags + n * NPROD;        // [64] partials-ready stamps
  unsigned* vf = flags + 256 + n * NPROD;  // [64] V-segment-ready stamps
  unsigned* ef = flags + 512;              // [256] epilogue rendezvous
  float* pbase = part + (((size_t)n) << 6) * P;  // batch partial base [64][P]
  float* prow = pbase + (size_t)rb * P;          // our post row (slot order)
  float* Vgn = Vg + n * P;                       // V vector (slot order)

  float creg[4][32];  // C * INV_EPS * log2e for this lane's 4 rows x 32 cols

  // ---------------- build phase ----------------
  {
    const int rr = t >> 4, d4 = (t & 15) * 4;
    float4 xv = *(const float4*)(x + xyb + (size_t)(i0 + rr) * DF + d4);
    sm.b.xs[rr * DF + d4 + 0] = xv.x;
    sm.b.xs[rr * DF + d4 + 1] = xv.y;
    sm.b.xs[rr * DF + d4 + 2] = xv.z;
    sm.b.xs[rr * DF + d4 + 3] = xv.w;
  }
  const int cl = t >> 1;         // y-row within 256-col chunk
  const int db = (t & 1) * 16;   // d-offset within 32-d half
#pragma unroll
  for (int k = 0; k < 8; ++k) {
    float acc[4][4];
#pragma unroll
    for (int r = 0; r < 4; ++r) acc[r][0] = acc[r][1] = acc[r][2] = acc[r][3] = 0.f;
#pragma unroll
    for (int h = 0; h < 2; ++h) {
      __syncthreads();  // protect previous ys tile use (also covers xs on first pass)
      {
        const float* yp = y + xyb + (size_t)(256 * k + cl) * DF + 32 * h + db;
        float4 q0 = *(const float4*)(yp + 0);
        float4 q1 = *(const float4*)(yp + 4);
        float4 q2 = *(const float4*)(yp + 8);
        float4 q3 = *(const float4*)(yp + 12);
        float* ys = sm.b.ys;
        ys[(db + 0) * 260 + cl] = q0.x;  ys[(db + 1) * 260 + cl] = q0.y;
        ys[(db + 2) * 260 + cl] = q0.z;  ys[(db + 3) * 260 + cl] = q0.w;
        ys[(db + 4) * 260 + cl] = q1.x;  ys[(db + 5) * 260 + cl] = q1.y;
        ys[(db + 6) * 260 + cl] = q1.z;  ys[(db + 7) * 260 + cl] = q1.w;
        ys[(db + 8) * 260 + cl] = q2.x;  ys[(db + 9) * 260 + cl] = q2.y;
        ys[(db + 10) * 260 + cl] = q2.z; ys[(db + 11) * 260 + cl] = q2.w;
        ys[(db + 12) * 260 + cl] = q3.x; ys[(db + 13) * 260 + cl] = q3.y;
        ys[(db + 14) * 260 + cl] = q3.z; ys[(db + 15) * 260 + cl] = q3.w;
      }
      __syncthreads();
#pragma unroll 8
      for (int dd = 0; dd < 32; ++dd) {
        float4 y4 = *(const float4*)&sm.b.ys[dd * 260 + 4 * l];
#pragma unroll
        for (int r = 0; r < 4; ++r) {
          float xv = sm.b.xs[(w * 4 + r) * DF + 32 * h + dd];  // wave-uniform broadcast
          float d0 = xv - y4.x; acc[r][0] = fmaf(d0, d0, acc[r][0]);
          float d1 = xv - y4.y; acc[r][1] = fmaf(d1, d1, acc[r][1]);
          float d2 = xv - y4.z; acc[r][2] = fmaf(d2, d2, acc[r][2]);
          float d3 = xv - y4.w; acc[r][3] = fmaf(d3, d3, acc[r][3]);
        }
      }
    }
#pragma unroll
    for (int r = 0; r < 4; ++r) {
      vfloat4 c4 = {acc[r][0], acc[r][1], acc[r][2], acc[r][3]};
      __builtin_nontemporal_store(c4,
          (vfloat4*)(Cout + cb + (size_t)(i0 + 4 * w + r) * P + 256 * k + 4 * l));
      creg[r][4 * k + 0] = acc[r][0] * SCALE;
      creg[r][4 * k + 1] = acc[r][1] * SCALE;
      creg[r][4 * k + 2] = acc[r][2] * SCALE;
      creg[r][4 * k + 3] = acc[r][3] * SCALE;
    }
  }
  __syncthreads();  // build->iter LDS union hazard

  // ---------------- 50 Sinkhorn iterations (scaled base-2 log domain) --------
  float U[4];
#pragma unroll 1
  for (int it = 0; it < MAX_ITER; ++it) {
    // ---- compute stage ----
    if (t < NPROD) {  // parallel poll of 64 reducer stamps (it=0 trivial)
      unsigned* f = vf + t;
      while (flag_load(f) < (unsigned)it) __builtin_amdgcn_s_sleep(1);
    }
    __syncthreads();
    {  // stage V (slot order) -> LDS, b128 stores
      float2 a = load_f2_agent((float2*)(Vgn + 4 * t));
      float2 b2 = load_f2_agent((float2*)(Vgn + 4 * t + 2));
      vfloat4 vv = {a.x, a.y, b2.x, b2.y};
      *(vfloat4*)&sm.c.v[4 * t] = vv;
    }
    __syncthreads();
    // un-swizzle into registers: creg slot i (col 256k+4l+e) <- V slot 256k+64e+l
    float vreg[32];
#pragma unroll
    for (int i = 0; i < 32; ++i)
      vreg[i] = sm.c.v[256 * (i >> 2) + 64 * (i & 3) + l];
    // u-update: U_i = l2mu - LSE2_j(V_j - C2_ij)
#pragma unroll
    for (int r = 0; r < 4; ++r) {
      float arg[32];
      float m = -3.4e38f;
#pragma unroll
      for (int i = 0; i < 32; ++i) {
        arg[i] = vreg[i] - creg[r][i];
        m = fmaxf(m, arg[i]);
      }
#pragma unroll
      for (int off = 32; off; off >>= 1) m = fmaxf(m, __shfl_xor(m, off));
      float s = 0.f;
#pragma unroll
      for (int i = 0; i < 32; ++i) s += EXP2(arg[i] - m);
#pragma unroll
      for (int off = 32; off; off >>= 1) s += __shfl_xor(s, off);
      U[r] = l2mu - (m + LOG2(s));
    }
    // v-update partials over this wave's 4 rows (per column)
    float pm[32], ps[32];
#pragma unroll
    for (int i = 0; i < 32; ++i) {
      float a0 = U[0] - creg[0][i];
      float a1 = U[1] - creg[1][i];
      float a2 = U[2] - creg[2][i];
      float a3 = U[3] - creg[3][i];
      float m = fmaxf(fmaxf(a0, a1), fmaxf(a2, a3));
      pm[i] = m;
      ps[i] = EXP2(a0 - m) + EXP2(a1 - m) + EXP2(a2 - m) + EXP2(a3 - m);
    }
    // combine 8 waves -> 4 -> 1 via LDS (slot idx = 256k + 64e + l: conflict-free)
    if (w >= 4) {
#pragma unroll
      for (int i = 0; i < 32; ++i) {
        int idx = 256 * (i >> 2) + 64 * (i & 3) + l;
        sm.c.m[w - 4][idx] = pm[i];
        sm.c.s[w - 4][idx] = ps[i];
      }
    }
    __syncthreads();
    if (w < 4) {
#pragma unroll
      for (int i = 0; i < 32; ++i) {
        int idx = 256 * (i >> 2) + 64 * (i & 3) + l;
        float M = pm[i], S = ps[i];
        lse_merge(M, S, sm.c.m[w][idx], sm.c.s[w][idx]);
        sm.c.m[w][idx] = M;
        sm.c.s[w][idx] = S;
      }
    }
    __syncthreads();
    // post single-float LSE partial per slot, coalesced
#pragma unroll
    for (int q = 0; q < 4; ++q) {
      int idx = t + 512 * q;
      float m0 = sm.c.m[0][idx], m1 = sm.c.m[1][idx];
      float m2 = sm.c.m[2][idx], m3 = sm.c.m[3][idx];
      float s0 = sm.c.s[0][idx], s1 = sm.c.s[1][idx];
      float s2 = sm.c.s[2][idx], s3 = sm.c.s[3][idx];
      float M = fmaxf(fmaxf(m0, m1), fmaxf(m2, m3));
      float S = s0 * EXP2(m0 - M) + s1 * EXP2(m1 - M)
              + s2 * EXP2(m2 - M) + s3 * EXP2(m3 - M);
      store_f_agent(prow + idx, M + LOG2(S));
    }
    __threadfence_block();  // vmcnt drain: retired sc1 stores visible at L3
    __syncthreads();
    if (t == 0) flag_store(&pf[rb], (unsigned)(it + 1));

    // ---- reduce stage: this block owns slots [rb*32, rb*32+32) ----
    if (t < NPROD) {  // parallel poll of 64 producer stamps
      unsigned* f = pf + t;
      while (flag_load(f) < (unsigned)(it + 1)) __builtin_amdgcn_s_sleep(1);
    }
    __syncthreads();
    {
      const int cs = t & 31;   // slot within our 32
      const int p = t >> 5;    // producer 0..15 (+16q below)
      const int s = rb * 32 + cs;
      // 128B-contiguous runs per half-wave (32 consecutive slots x 1 producer)
      float L0 = load_f_agent(pbase + (size_t)(p + 0) * P + s);
      float L1 = load_f_agent(pbase + (size_t)(p + 16) * P + s);
      float L2 = load_f_agent(pbase + (size_t)(p + 32) * P + s);
      float L3 = load_f_agent(pbase + (size_t)(p + 48) * P + s);
      float M = fmaxf(fmaxf(L0, L1), fmaxf(L2, L3));
      float S = EXP2(L0 - M) + EXP2(L1 - M) + EXP2(L2 - M) + EXP2(L3 - M);
      // merge producer pair across the wave-half boundary (p <-> p^1 via lane^32)
      float Mo = __shfl_xor(M, 32), So = __shfl_xor(S, 32);
      lse_merge(M, S, Mo, So);
      if (l < 32) { sm.r.mm[w][l] = M; sm.r.ss[w][l] = S; }
    }
    __syncthreads();
    if (t < 32) {
      float Mm = sm.r.mm[0][t], Ss = sm.r.ss[0][t];
#pragma unroll
      for (int w2 = 1; w2 < 8; ++w2)
        lse_merge(Mm, Ss, sm.r.mm[w2][t], sm.r.ss[w2][t]);
      // V write: 32 CONSECUTIVE floats (slot order)
      store_f_agent(Vgn + rb * 32 + t, l2mu - (Mm + LOG2(Ss)));
    }
    __threadfence_block();
    __syncthreads();
    if (t == 0) flag_store(&vf[rb], (unsigned)(it + 1));
  }

  // ---------------- epilogue: pi and cost ----------------
  if (t < NPROD) {  // final V^(50)
    unsigned* f = vf + t;
    while (flag_load(f) < (unsigned)MAX_ITER) __builtin_amdgcn_s_sleep(1);
  }
  __syncthreads();
  {
    float2 a = load_f2_agent((float2*)(Vgn + 4 * t));
    float2 b2 = load_f2_agent((float2*)(Vgn + 4 * t + 2));
    vfloat4 vv = {a.x, a.y, b2.x, b2.y};
    *(vfloat4*)&sm.c.v[4 * t] = vv;
  }
  __syncthreads();
  float vreg2[32];
#pragma unroll
  for (int i = 0; i < 32; ++i)
    vreg2[i] = sm.c.v[256 * (i >> 2) + 64 * (i & 3) + l];
  // part/Vg live inside the pi region: GLOBAL rendezvous before overwrite
  if (t == 0) flag_store(&ef[b], 1u);
  if (t < 256) {
    unsigned* f = &ef[t];
    while (flag_load(f) < 1u) __builtin_amdgcn_s_sleep(1);
  }
  __syncthreads();
  float csum = 0.f;
#pragma unroll
  for (int r = 0; r < 4; ++r) {
    const size_t rowb = cb + (size_t)(i0 + 4 * w + r) * P;
#pragma unroll
    for (int k = 0; k < 8; ++k) {
      vfloat4 p4;
      p4.x = EXP2(U[r] + vreg2[4 * k + 0] - creg[r][4 * k + 0]);
      p4.y = EXP2(U[r] + vreg2[4 * k + 1] - creg[r][4 * k + 1]);
      p4.z = EXP2(U[r] + vreg2[4 * k + 2] - creg[r][4 * k + 2]);
      p4.w = EXP2(U[r] + vreg2[4 * k + 3] - creg[r][4 * k + 3]);
      csum += p4.x * creg[r][4 * k + 0] + p4.y * creg[r][4 * k + 1]
            + p4.z * creg[r][4 * k + 2] + p4.w * creg[r][4 * k + 3];
      __builtin_nontemporal_store(p4, (vfloat4*)(pi + rowb + 256 * k + 4 * l));
    }
  }
  float cs = csum * C2N;  // creg = C*INV_EPS*log2e -> sum(pi*creg)*EPS*ln2
#pragma unroll
  for (int off = 32; off; off >>= 1) cs += __shfl_xor(cs, off);
  if (l == 0) atomicAdd(cost + n, cs);
}

// ===========================================================================
// Fallback path (round-1 kernels, known-good) in case cooperative launch fails
// ===========================================================================
__global__ __launch_bounds__(256) void build_c(const float* __restrict__ x,
                                               const float* __restrict__ y,
                                               float* __restrict__ C,
                                               float* __restrict__ CT) {
  __shared__ float xs[DF][68];
  __shared__ float ys[DF][68];
  const int n = blockIdx.z;
  const int i0 = blockIdx.y * 64, j0 = blockIdx.x * 64;
  const int t = threadIdx.x;
  const int lr = t >> 4, c4 = (t & 15) * 4;
  const size_t xb = (size_t)n * P * DF;
  for (int rr = lr; rr < 64; rr += 16) {
    float4 xv = *(const float4*)(x + xb + (size_t)(i0 + rr) * DF + c4);
    float4 yv = *(const float4*)(y + xb + (size_t)(j0 + rr) * DF + c4);
    xs[c4 + 0][rr] = xv.x; xs[c4 + 1][rr] = xv.y;
    xs[c4 + 2][rr] = xv.z; xs[c4 + 3][rr] = xv.w;
    ys[c4 + 0][rr] = yv.x; ys[c4 + 1][rr] = yv.y;
    ys[c4 + 2][rr] = yv.z; ys[c4 + 3][rr] = yv.w;
  }
  __syncthreads();
  const int ty = t >> 4, tx = t & 15;
  float acc[4][4];
#pragma unroll
  for (int e = 0; e < 4; ++e)
#pragma unroll
    for (int f = 0; f < 4; ++f) acc[e][f] = 0.f;
#pragma unroll 4
  for (int d = 0; d < DF; ++d) {
    float4 a4 = *(const float4*)&xs[d][4 * ty];
    float4 b4 = *(const float4*)&ys[d][4 * tx];
    float av[4] = {a4.x, a4.y, a4.z, a4.w};
    float bv[4] = {b4.x, b4.y, b4.z, b4.w};
#pragma unroll
    for (int e = 0; e < 4; ++e)
#pragma unroll
      for (int f = 0; f < 4; ++f) {
        float df = av[e] - bv[f];
        acc[e][f] = fmaf(df, df, acc[e][f]);
      }
  }
  const size_t cbase = (size_t)n * P * P;
#pragma unroll
  for (int e = 0; e < 4; ++e) {
    float4 v4 = make_float4(acc[e][0], acc[e][1], acc[e][2], acc[e][3]);
    *(float4*)(C + cbase + (size_t)(i0 + 4 * ty + e) * P + (j0 + 4 * tx)) = v4;
  }
#pragma unroll
  for (int f = 0; f < 4; ++f) {
    float4 v4 = make_float4(acc[0][f], acc[1][f], acc[2][f], acc[3][f]);
    *(float4*)(CT + cbase + (size_t)(j0 + 4 * tx + f) * P + (i0 + 4 * ty)) = v4;
  }
}

__global__ __launch_bounds__(256) void lse_pass(const float* __restrict__ M,
                                                const float* __restrict__ wv_,
                                                float* __restrict__ out,
                                                float log_w) {
  __shared__ float red[8];
  const int b = blockIdx.x;
  const int n = b >> 11;
  const int t = threadIdx.x;
  const float4* row = (const float4*)(M + (size_t)b * P);
  const float4* wv = (const float4*)(wv_ + (size_t)n * P);
  float4 c0 = row[t], c1 = row[t + 256];
  float4 w0 = wv[t], w1 = wv[t + 256];
  float a[8];
  a[0] = (w0.x - c0.x) * INV_EPS; a[1] = (w0.y - c0.y) * INV_EPS;
  a[2] = (w0.z - c0.z) * INV_EPS; a[3] = (w0.w - c0.w) * INV_EPS;
  a[4] = (w1.x - c1.x) * INV_EPS; a[5] = (w1.y - c1.y) * INV_EPS;
  a[6] = (w1.z - c1.z) * INV_EPS; a[7] = (w1.w - c1.w) * INV_EPS;
  float mx = a[0];
#pragma unroll
  for (int k = 1; k < 8; ++k) mx = fmaxf(mx, a[k]);
#pragma unroll
  for (int o = 32; o > 0; o >>= 1) mx = fmaxf(mx, __shfl_xor(mx, o));
  if ((t & 63) == 0) red[t >> 6] = mx;
  __syncthreads();
  mx = fmaxf(fmaxf(red[0], red[1]), fmaxf(red[2], red[3]));
  float s = 0.f;
#pragma unroll
  for (int k = 0; k < 8; ++k) s += __expf(a[k] - mx);
#pragma unroll
  for (int o = 32; o > 0; o >>= 1) s += __shfl_xor(s, o);
  if ((t & 63) == 0) red[4 + (t >> 6)] = s;
  __syncthreads();
  if (t == 0) {
    float S = red[4] + red[5] + red[6] + red[7];
    out[b] = EPS * (log_w - (mx + __logf(S)));
  }
}

__global__ __launch_bounds__(256) void final_pass(const float* __restrict__ C,
                                                  const float* __restrict__ u,
                                                  const float* __restrict__ v,
                                                  float* __restrict__ pi,
                                                  float* __restrict__ cost) {
  __shared__ float red[4];
  const int b = blockIdx.x;
  const int n = b >> 11;
  const int t = threadIdx.x;
  const float ui = u[b];
  const float4* row = (const float4*)(C + (size_t)b * P);
  const float4* vv = (const float4*)(v + (size_t)n * P);
  float4* prow = (float4*)(pi + (size_t)b * P);
  float local = 0.f;
#pragma unroll
  for (int h = 0; h < 2; ++h) {
    float4 c = row[t + 256 * h];
    float4 vw = vv[t + 256 * h];
    float4 p;
    p.x = __expf((ui + vw.x - c.x) * INV_EPS);
    p.y = __expf((ui + vw.y - c.y) * INV_EPS);
    p.z = __expf((ui + vw.z - c.z) * INV_EPS);
    p.w = __expf((ui + vw.w - c.w) * INV_EPS);
    prow[t + 256 * h] = p;
    local += p.x * c.x + p.y * c.y + p.z * c.z + p.w * c.w;
  }
#pragma unroll
  for (int o = 32; o > 0; o >>= 1) local += __shfl_xor(local, o);
  if ((t & 63) == 0) red[t >> 6] = local;
  __syncthreads();
  if (t == 0) {
    float S = red[0] + red[1] + red[2] + red[3];
    atomicAdd(cost + n, S);
  }
}

extern "C" void kernel_launch(void* const* d_in, const int* in_sizes, int n_in,
                              void* d_out, int out_size, void* d_ws, size_t ws_size,
                              hipStream_t stream) {
  const float* x = (const float*)d_in[0];
  const float* y = (const float*)d_in[1];
  float* cost = (float*)d_out;                 // 4 floats
  float* pi = cost + 4;                        // 4*2048*2048
  float* C = pi + (size_t)NB * P * P;          // 4*2048*2048
  // scratch carved out of the pi output slot (fully overwritten by epilogue):
  float* part = pi;                                    // 2 MB of 4B partials
  float* Vg = pi + (size_t)NB * NPROD * P;             // 32 KB V vector
  unsigned* flags = (unsigned*)d_ws;                   // pf/vf/ef stamps

  (void)hipMemsetAsync(cost, 0, NB * sizeof(float), stream);
  (void)hipMemsetAsync(Vg, 0, NB * P * sizeof(float), stream);
  (void)hipMemsetAsync(flags, 0, 4096, stream);

  float lmu = logf(1.0f / (float)P + 1e-8f);    // nat log (fallback)
  float l2mu = log2f(1.0f / (float)P + 1e-8f);  // base-2 log (main)

  void* args[] = {(void*)&x, (void*)&y, (void*)&C, (void*)&pi,
                  (void*)&cost, (void*)&part, (void*)&Vg, (void*)&flags,
                  (void*)&l2mu};
  hipError_t err = hipLaunchCooperativeKernel((void*)sinkhorn_all, dim3(NBLK),
                                              dim3(TPB), args, 0, stream);
  if (err != hipSuccess) {
    // fallback: round-1 multi-kernel path (deterministically taken if coop fails)
    float* u = (float*)d_ws;
    float* v = u + NB * P;
    (void)hipMemsetAsync(v, 0, NB * P * sizeof(float), stream);
    float* CT = pi;
    build_c<<<dim3(32, 32, 4), 256, 0, stream>>>(x, y, C, CT);
    for (int it = 0; it < MAX_ITER; ++it) {
      lse_pass<<<NB * P, 256, 0, stream>>>(C, v, u, lmu);
      lse_pass<<<NB * P, 256, 0, stream>>>(CT, u, v, lmu);
    }
    final_pass<<<NB * P, 256, 0, stream>>>(C, u, v, pi, cost);
  }
}